// Round 8
// baseline (294.657 us; speedup 1.0000x reference)
//
#include <hip/hip_runtime.h>

// MassConservingLSTMCell — round 13: wave-local rownorm, ZERO barriers in the
// main loop. R5-R12 falsified: prefetch depth, occupancy, reg-vs-LDS B,
// vmcnt discipline, B volume, atomics-vs-stores — all ~80-95us, MfmaUtil
// 16-19%. Never varied: the per-u block-wide barrier (8-32x/block) that
// lock-steps 8 waves for the cross-wave rownorm exchange (R12: ~1200cyc per
// epilogue instance + 1M bank conflicts). R13: wave tile = 16 rows x ALL 256
// cols (acc[16] f32x4) -> rownorm = reg-adds + 4-round shfl_xor butterfly,
// fully wave-local. One barrier after staging, then none until the tail.
// Block = 64 rows x 16 u (8 waves = 4 stripes x 2 u-halves); grid = 16 Mb x
// 16 (ug,uh) = 256 blocks, XCD pin bid%8=ug. Tail: 4-way atomicAdd into 8
// zeroed partial copies (k_prep zeroes 8 MB). k_post reduces 8 copies.
//
// B=1024, U=256, F=31, D=288 (9 k-chunks of 32).

#define EPS_L1 1e-7f

constexpr int BB  = 1024;
constexpr int U   = 256;
constexpr int F   = 31;
constexpr int D   = 1 + U + F;      // 288
constexpr int NBV = BB * U;         // 262144
constexpr int NCH = D / 32;         // 9
constexpr int UIMGB = NCH * 16384;  // 147456 B per u-slice B-image
constexpr size_t WTB_BYTES  = (size_t)258 * UIMGB;
constexpr size_t FEAT_BYTES = (size_t)BB * D * 2;

typedef float f32x4 __attribute__((ext_vector_type(4)));
typedef short bf16x8 __attribute__((ext_vector_type(8)));

__device__ __forceinline__ unsigned f2bf(float x) {
  union { float f; unsigned u; } v; v.f = x;
  unsigned r = v.u + 0x7FFFu + ((v.u >> 16) & 1u);
  return r >> 16;
}

#define GLDS16(gp, lp)                                                        \
  __builtin_amdgcn_global_load_lds(                                          \
      (const __attribute__((address_space(1))) void*)(gp),                   \
      (__attribute__((address_space(3))) void*)(lp), 16, 0, 0)

#define MFMA16(a, b, c) __builtin_amdgcn_mfma_f32_16x16x32_bf16((a), (b), (c), 0, 0, 0)

// ---------------------------------------------------------------- k_prep
// grid 2402 x 256:
//   [0..2322)    weight transform, block = (u, c) single chunk
//   [2322..2338) features -> A fragment images (16 x 64-row)
//   [2338..2402) zero partial[0..8) (8 MB — atomic accumulation targets)
__global__ __launch_bounds__(256) void k_prep(
    const float* __restrict__ lc, const float* __restrict__ p,
    const float* __restrict__ other,
    const float* __restrict__ Wi, const float* __restrict__ Wr,
    const float* __restrict__ Wo,
    short* __restrict__ WtB, short* __restrict__ featImg,
    float* __restrict__ partial) {
  __shared__ unsigned tw[256][17];   // [v][k-pair], odd pitch: <=2-way conflicts
  __shared__ float inv_s[64];
  const int bid = blockIdx.x, t = threadIdx.x;

  if (bid < 2322) {
    // ---- weight transform: one 32k x 256v chunk of u-slice (u = bid/9, c = bid%9)
    const int u = bid / 9, c = bid % 9;
    const float* src; long ld;
    if (u < 256)       { src = Wr + (size_t)u * 256; ld = 65536; }
    else if (u == 256) { src = Wi; ld = 256; }
    else               { src = Wo; ld = 256; }

    // phase 1: coalesced float4 loads of two k-rows, pack k-pairs into u32,
    // transposed stage tw[v][kp]
    const int kp = t >> 4, f = t & 15;           // kp in [0,16), f in [0,16)
    const float* r0 = src + (size_t)(c * 32 + 2 * kp) * ld;
    const float* r1 = r0 + ld;
#pragma unroll
    for (int i = 0; i < 4; ++i) {
      const int v0 = f * 4 + i * 64;
      const float4 a = *(const float4*)(r0 + v0);
      const float4 b = *(const float4*)(r1 + v0);
      tw[v0 + 0][kp] = f2bf(a.x) | (f2bf(b.x) << 16);
      tw[v0 + 1][kp] = f2bf(a.y) | (f2bf(b.y) << 16);
      tw[v0 + 2][kp] = f2bf(a.z) | (f2bf(b.z) << 16);
      tw[v0 + 3][kp] = f2bf(a.w) | (f2bf(b.w) << 16);
    }
    __syncthreads();

    // phase 2: fragment gather — per fragment 4x ds_read_b32 + one 16B store.
    const int lane = t & 63, wave = t >> 6;
    const int g = lane >> 4, l15 = lane & 15;
    short* dst = WtB + (size_t)u * 73728 + (size_t)c * 16 * 512;
#pragma unroll
    for (int ii = 0; ii < 4; ++ii) {
      const int n0 = wave * 4 + ii;
      const int row = n0 * 16 + l15;
      union { unsigned u4[4]; bf16x8 h; } cv;
#pragma unroll
      for (int j = 0; j < 4; ++j) cv.u4[j] = tw[row][g * 4 + j];
      *(bf16x8*)(dst + (size_t)n0 * 512 + lane * 8) = cv.h;
    }
  } else if (bid < 2338) {
    // ---- features -> A fragment image (64-row block mb)
    const int mb = bid - 2322;
    const int b0 = mb * 64;
    const int row = t >> 2, q = t & 3;
    const float4* lp = (const float4*)(lc + (size_t)(b0 + row) * 256 + q * 64);
    float s = 0.f;
#pragma unroll
    for (int j = 0; j < 16; ++j) {
      const float4 v = lp[j];
      s += fabsf(v.x) + fabsf(v.y) + fabsf(v.z) + fabsf(v.w);
    }
    s += __shfl_xor(s, 1, 64);
    s += __shfl_xor(s, 2, 64);
    if (q == 0) inv_s[row] = 1.f / (s + EPS_L1);
    __syncthreads();
#pragma unroll
    for (int i = 0; i < 9; ++i) {
      const int idx = i * 256 + t;
      const int reg = idx >> 6, l = idx & 63;
      const int c = reg >> 2, mt = reg & 3;
      const int lrow = mt * 16 + (l & 15);
      const int grow = b0 + lrow;
      const int k0 = c * 32 + (l >> 4) * 8;
      bf16x8 h;
#pragma unroll
      for (int j = 0; j < 8; ++j) {
        const int k = k0 + j;
        float v;
        if (k == 0) v = p[grow];
        else if (k <= 256) v = lc[(size_t)grow * 256 + (k - 1)] * inv_s[lrow];
        else v = other[(size_t)grow * 31 + (k - 257)];
        h[j] = (short)f2bf(v);
      }
      *(bf16x8*)(featImg + (size_t)mb * 18432 + (size_t)reg * 512 + l * 8) = h;
    }
  } else {
    // ---- zero partial copies 0..7 (8 MB)
    float4* cs4 = (float4*)partial;
    const int base = (bid - 2338) * 8192 + t;
    const float4 z = {0.f, 0.f, 0.f, 0.f};
#pragma unroll
    for (int k2 = 0; k2 < 32; ++k2) cs4[base + k2 * 256] = z;
  }
}

// ---------------------------------------------------------------- k_heavyR13
// 256 blocks = 16 Mb (64 rows) x 16 q (ug = q&7 -> XCD pin, uh = q>>3).
// 512 thr, 8 waves = 4 row-stripes x 2 u-halves; wave = 16 rows x 256 cols,
// 8 u's. Rownorm fully wave-local (reg-sum + 4x shfl_xor butterfly).
// ZERO barriers after the staging sync. Tail: 4-way atomicAdd into copy ug.
__global__ __launch_bounds__(512, 2) void k_heavyR13(
    const short* __restrict__ featImg, const short* __restrict__ WtB,
    const float* __restrict__ lc, const float* __restrict__ br,
    float* __restrict__ partial) {
  __shared__ short aT[18432];        // 36864 B: one 64-row image [c][mt][1KB]
  __shared__ float brs[16 * 256];    // 16 KB: br cols for u0..u0+16
  __shared__ float lcs[16][66];      // lc[b0..b0+64) x u0..u0+16, [u_loc][row]

  const int t = threadIdx.x, lane = t & 63, w = t >> 6;
  const int l15 = lane & 15, quad = lane >> 4;
  const int bid = blockIdx.x;
  const int Mb = bid >> 4, q = bid & 15;
  const int ug = q & 7, uh = q >> 3;         // bid%8 = ug = XCD pin
  const int b0 = Mb * 64;
  const int u0 = ug * 32 + uh * 16;
  const int s = w & 3, uhh = w >> 2;
  const int uw0 = u0 + uhh * 8;

  // ---- stage: A image + br slice via GLDS; lc slice via plain stores
  {
    const char* gA = (const char*)featImg + (size_t)Mb * 36864;
    char* lA = (char*)aT;
#pragma unroll
    for (int i = 0; i < 5; ++i) {
      const int off = i * 8192 + t * 16;
      if (off < 36864) GLDS16(gA + off, lA + off);   // guard: t<256, wave-uniform
    }
    const char* gB = (const char*)(br + (size_t)u0 * 256);
    char* lB = (char*)brs;
    GLDS16(gB + t * 16, lB + t * 16);
    GLDS16(gB + 8192 + t * 16, lB + 8192 + t * 16);
  }
#pragma unroll
  for (int i = 0; i < 2; ++i) {
    const int idx = i * 512 + t;
    const int row = idx >> 4, j = idx & 15;
    lcs[j][row] = lc[(size_t)(b0 + row) * 256 + u0 + j];
  }

  f32x4 acc[16], outa[16];
#pragma unroll
  for (int n = 0; n < 16; ++n)
#pragma unroll
    for (int r = 0; r < 4; ++r) { acc[n][r] = 0.f; outa[n][r] = 0.f; }

  __syncthreads();   // the ONLY block-wide sync (drains staging GLDS)

  const char* aBase = (const char*)aT + s * 1024 + lane * 16;   // + c*4096
  const char* bBase = (const char*)WtB + (size_t)uw0 * UIMGB + lane * 16;

  for (int uu = 0; uu < 8; ++uu) {
    const char* bU = bBase + (size_t)uu * UIMGB;

#pragma unroll
    for (int c = 0; c < 9; ++c) {
      const bf16x8 a = *(const bf16x8*)(aBase + c * 4096);
      const char* bC = bU + (size_t)c * 16384;
#pragma unroll
      for (int n = 0; n < 16; ++n) {
        const bf16x8 b = *(const bf16x8*)(bC + n * 1024);
        acc[n] = MFMA16(a, b, acc[n]);
      }
    }

    // ---- wave-local epilogue: bias+relu, 256-col rowsum, normalize+contract
    const int ul = uhh * 8 + uu;
    float sm[4];
#pragma unroll
    for (int r = 0; r < 4; ++r) sm[r] = 0.f;
#pragma unroll
    for (int n = 0; n < 16; ++n) {
      const float bv = brs[ul * 256 + n * 16 + l15];
#pragma unroll
      for (int r = 0; r < 4; ++r) {
        const float rv = fmaxf(acc[n][r] + bv, 0.f);
        acc[n][r] = rv;
        sm[r] += rv;
      }
    }
#pragma unroll
    for (int msk = 1; msk < 16; msk <<= 1)
#pragma unroll
      for (int r = 0; r < 4; ++r)
        sm[r] += __shfl_xor(sm[r], msk, 64);   // butterfly allreduce over l15
#pragma unroll
    for (int r = 0; r < 4; ++r) {
      const int row = s * 16 + quad * 4 + r;
      const float alpha = lcs[ul][row] * __builtin_amdgcn_rcpf(sm[r]);
#pragma unroll
      for (int n = 0; n < 16; ++n) {
        outa[n][r] = fmaf(alpha, acc[n][r], outa[n][r]);
        acc[n][r] = 0.f;
      }
    }
  }

  // ---- tail: 4-way atomicAdd into zeroed copy ug
  float* pc = partial + ((size_t)ug << 18);
#pragma unroll
  for (int r = 0; r < 4; ++r) {
    const int grow = b0 + s * 16 + quad * 4 + r;
#pragma unroll
    for (int n = 0; n < 16; ++n)
      atomicAdd(&pc[(size_t)grow * 256 + n * 16 + l15], outa[n][r]);
  }
}

// ---------------------------------------------------------------- k_postR12
// 64 blocks x 512 thr: 16 rows each. Reduce 8 partial copies into LDS,
// then gates MFMA (ig,og in regs) + final combine.
__global__ __launch_bounds__(512, 2) void k_postR12(
    const short* __restrict__ featImg, const short* __restrict__ WtB,
    const float* __restrict__ bi, const float* __restrict__ bo,
    const float* __restrict__ p, const float* __restrict__ partial, int npart,
    float* __restrict__ dout) {
  __shared__ short aT9[9 * 512];       // 9 KB: A fragments (c=0..8) for 16 rows
  __shared__ float cs[16 * 256];       // 16 KB: reduced cell_sys tile
  __shared__ float rsum[16][12];
  __shared__ float ps[16];

  const int t = threadIdx.x, lane = t & 63, cg = t >> 6;
  const int quad = lane >> 4, l15 = lane & 15;
  const int mb16 = blockIdx.x, b0 = mb16 * 16;
  const int mb = mb16 >> 2, mt = mb16 & 3;

  // stage A fragments: regs (c*4 + mt), c = 0..8  -> aT9[c*1024B]
  {
    const char* gsrc = (const char*)featImg + (size_t)mb * 36864 + mt * 1024;
    char* ldst = (char*)aT9;
    GLDS16(gsrc + (size_t)(t >> 6) * 4096 + (t & 63) * 16, ldst + t * 16);
    if (t < 64)
      GLDS16(gsrc + (size_t)8 * 4096 + t * 16, ldst + 8192 + t * 16);
  }
  if (t < 16) ps[t] = p[b0 + t];

  // reduce npart partial copies for rows [b0, b0+16) into cs
  {
    const float* pbase = partial + (size_t)b0 * 256;
    f32x4 s0 = {0.f, 0.f, 0.f, 0.f}, s1 = {0.f, 0.f, 0.f, 0.f};
    for (int ug = 0; ug < npart; ++ug) {
      const f32x4* pp = (const f32x4*)(pbase + (size_t)ug * 262144);
      s0 += pp[t];
      s1 += pp[512 + t];
    }
    ((f32x4*)cs)[t] = s0;
    ((f32x4*)cs)[512 + t] = s1;
  }

  f32x4 acc[2];
#pragma unroll
  for (int n = 0; n < 2; ++n)
#pragma unroll
    for (int r = 0; r < 4; ++r) acc[n][r] = 0.f;

  const char* bptr = (const char*)WtB + (size_t)256 * UIMGB + cg * 2048 + lane * 16;
  bf16x8 cb0 = *(const bf16x8*)(bptr);
  bf16x8 cb1 = *(const bf16x8*)(bptr + 1024);
  bf16x8 nb0 = *(const bf16x8*)(bptr + 16384);
  bf16x8 nb1 = *(const bf16x8*)(bptr + 16384 + 1024);
  bptr += 32768;

  __syncthreads();   // A fragments + cs resident

  float ig0[4], ig1[4], og0[4], og1[4];

#pragma unroll
  for (int g = 0; g < 2; ++g) {
    const float* bias = (g == 0) ? bi : bo;
    const float bv0 = bias[cg * 32 + l15];
    const float bv1 = bias[cg * 32 + 16 + l15];
#pragma unroll
    for (int c = 0; c < 9; ++c) {
      const bf16x8 pb0 = *(const bf16x8*)(bptr);
      const bf16x8 pb1 = *(const bf16x8*)(bptr + 1024);
      bptr += 16384;
      const bf16x8 a0 = *(const bf16x8*)((const char*)aT9 + c * 1024 + lane * 16);
      acc[0] = MFMA16(a0, cb0, acc[0]);
      acc[1] = MFMA16(a0, cb1, acc[1]);
      cb0 = nb0; cb1 = nb1; nb0 = pb0; nb1 = pb1;
    }

#pragma unroll
    for (int r = 0; r < 4; ++r) {
      const float v0 = 1.f / (1.f + __expf(-(acc[0][r] + bv0)));
      const float v1 = 1.f / (1.f + __expf(-(acc[1][r] + bv1)));
      if (g == 0) { ig0[r] = v0; ig1[r] = v1; }
      else        { og0[r] = v0; og1[r] = v1; }
      acc[0][r] = 0.f;
      acc[1][r] = 0.f;
    }

    if (g == 0) {
      float sm[4];
#pragma unroll
      for (int r = 0; r < 4; ++r) sm[r] = ig0[r] + ig1[r];
#pragma unroll
      for (int msk = 1; msk < 16; msk <<= 1)
#pragma unroll
        for (int r = 0; r < 4; ++r)
          sm[r] += __shfl_xor(sm[r], msk, 64);
      if (l15 == 0) {
#pragma unroll
        for (int r = 0; r < 4; ++r)
          rsum[quad * 4 + r][cg] = sm[r];
      }
      __syncthreads();
#pragma unroll
      for (int r = 0; r < 4; ++r) {
        const int row = quad * 4 + r;
        const float4 ra = *(const float4*)&rsum[row][0];
        const float4 rb = *(const float4*)&rsum[row][4];
        const float inv = 1.f / (((ra.x + ra.y) + (ra.z + ra.w)) +
                                 ((rb.x + rb.y) + (rb.z + rb.w)));
        ig0[r] *= inv;
        ig1[r] *= inv;
      }
    }
  }

#pragma unroll
  for (int r = 0; r < 4; ++r) {
    const int row = quad * 4 + r;
    const float pr = ps[row];
    const int ci = row * 256 + cg * 32 + l15;
    const size_t base = (size_t)(b0 + row) * 256 + cg * 32 + l15;
    {
      const float cand = fmaf(ig0[r], pr, cs[ci]);
      dout[base] = (1.f - og0[r]) * cand;
      dout[NBV + base] = og0[r] * cand;
    }
    {
      const float cand = fmaf(ig1[r], pr, cs[ci + 16]);
      dout[base + 16] = (1.f - og1[r]) * cand;
      dout[NBV + base + 16] = og1[r] * cand;
    }
  }
}

// ---------------------------------------------------------------- launch
extern "C" void kernel_launch(void* const* d_in, const int* in_sizes, int n_in,
                              void* d_out, int out_size, void* d_ws, size_t ws_size,
                              hipStream_t stream) {
  const float* lc    = (const float*)d_in[0];
  const float* p     = (const float*)d_in[1];
  const float* other = (const float*)d_in[2];
  const float* Wi    = (const float*)d_in[3];
  const float* bi    = (const float*)d_in[4];
  const float* Wr    = (const float*)d_in[5];
  const float* br    = (const float*)d_in[6];
  const float* Wo    = (const float*)d_in[7];
  const float* bo    = (const float*)d_in[8];
  float* out = (float*)d_out;

  char* wsb = (char*)d_ws;
  short* WtB      = (short*)wsb;
  short* featImg  = (short*)(wsb + WTB_BYTES);
  float* partial  = (float*)(wsb + WTB_BYTES + FEAT_BYTES);

  k_prep<<<2402, 256, 0, stream>>>(lc, p, other, Wi, Wr, Wo, WtB, featImg, partial);
  k_heavyR13<<<256, 512, 0, stream>>>(featImg, WtB, lc, br, partial);
  k_postR12<<<64, 512, 0, stream>>>(featImg, WtB, bi, bo, p, partial, 8, out);
}

// Round 9
// 211.841 us; speedup vs baseline: 1.3909x; 1.3909x over previous
//
#include <hip/hip_runtime.h>

// MassConservingLSTMCell — round 14: composite-best banking.
// R13 post-mortem: wave-local-norm tile (acc+outa=128 regs) left the compiler
// zero registers to hoist 16 B-loads/c-iter -> serialized LLC latency, 2x
// regression. Ledger: 8 k_heavy structures, floor = 78.6us (R5 form, R0 bench);
// prep/post each <78us; non-heavy gap stable ~130us. This round reunites the
// individually-best components, never before run together:
//   k_heavy  = R0's k_heavyR5 verbatim (78.6us: 8 Mb x 32 ug, 512 thr,
//              2rh x 4cq, 4m x 4n, dist-2 B reg prefetch, full __syncthreads
//              epilogue, atomic accumulate into cell_sys)
//   k_prep   = R3's single-chunk weight transform (best measured gap)
//   k_post   = R8's 64-block fused gates+combine
//
// B=1024, U=256, F=31, D=288 (9 k-chunks of 32).

#define EPS_L1 1e-7f

constexpr int BB  = 1024;
constexpr int U   = 256;
constexpr int F   = 31;
constexpr int D   = 1 + U + F;      // 288
constexpr int NBV = BB * U;         // 262144
constexpr int NCH = D / 32;         // 9
constexpr int UIMGB = NCH * 16384;  // 147456 B per u-slice B-image
constexpr size_t WTB_BYTES  = (size_t)258 * UIMGB;
constexpr size_t FEAT_BYTES = (size_t)BB * D * 2;

typedef float f32x4 __attribute__((ext_vector_type(4)));
typedef short bf16x8 __attribute__((ext_vector_type(8)));

__device__ __forceinline__ unsigned f2bf(float x) {
  union { float f; unsigned u; } v; v.f = x;
  unsigned r = v.u + 0x7FFFu + ((v.u >> 16) & 1u);
  return r >> 16;
}

#define GLDS16(gp, lp)                                                        \
  __builtin_amdgcn_global_load_lds(                                          \
      (const __attribute__((address_space(1))) void*)(gp),                   \
      (__attribute__((address_space(3))) void*)(lp), 16, 0, 0)

#define MFMA16(a, b, c) __builtin_amdgcn_mfma_f32_16x16x32_bf16((a), (b), (c), 0, 0, 0)

// ---------------------------------------------------------------- k_prep
// grid 2346 x 256:
//   [0..2322)    weight transform, block = (u, c) single chunk
//   [2322..2338) features -> A fragment images (16 x 64-row)
//   [2338..2346) zero cell_sys (1 MB)
__global__ __launch_bounds__(256) void k_prep(
    const float* __restrict__ lc, const float* __restrict__ p,
    const float* __restrict__ other,
    const float* __restrict__ Wi, const float* __restrict__ Wr,
    const float* __restrict__ Wo,
    short* __restrict__ WtB, short* __restrict__ featImg,
    float* __restrict__ cell_sys) {
  __shared__ unsigned tw[256][17];   // [v][k-pair], odd pitch: <=2-way conflicts
  __shared__ float inv_s[64];
  const int bid = blockIdx.x, t = threadIdx.x;

  if (bid < 2322) {
    // ---- weight transform: one 32k x 256v chunk of u-slice (u = bid/9, c = bid%9)
    const int u = bid / 9, c = bid % 9;
    const float* src; long ld;
    if (u < 256)       { src = Wr + (size_t)u * 256; ld = 65536; }
    else if (u == 256) { src = Wi; ld = 256; }
    else               { src = Wo; ld = 256; }

    // phase 1: coalesced float4 loads of two k-rows, pack k-pairs into u32,
    // transposed stage tw[v][kp]
    const int kp = t >> 4, f = t & 15;           // kp in [0,16), f in [0,16)
    const float* r0 = src + (size_t)(c * 32 + 2 * kp) * ld;
    const float* r1 = r0 + ld;
#pragma unroll
    for (int i = 0; i < 4; ++i) {
      const int v0 = f * 4 + i * 64;
      const float4 a = *(const float4*)(r0 + v0);
      const float4 b = *(const float4*)(r1 + v0);
      tw[v0 + 0][kp] = f2bf(a.x) | (f2bf(b.x) << 16);
      tw[v0 + 1][kp] = f2bf(a.y) | (f2bf(b.y) << 16);
      tw[v0 + 2][kp] = f2bf(a.z) | (f2bf(b.z) << 16);
      tw[v0 + 3][kp] = f2bf(a.w) | (f2bf(b.w) << 16);
    }
    __syncthreads();

    // phase 2: fragment gather — per fragment 4x ds_read_b32 (k-run is
    // contiguous in tw rows) + one 16B store. Layout identical to old WtB.
    const int lane = t & 63, wave = t >> 6;
    const int g = lane >> 4, l15 = lane & 15;
    short* dst = WtB + (size_t)u * 73728 + (size_t)c * 16 * 512;
#pragma unroll
    for (int ii = 0; ii < 4; ++ii) {
      const int n0 = wave * 4 + ii;
      const int row = n0 * 16 + l15;
      union { unsigned u4[4]; bf16x8 h; } cv;
#pragma unroll
      for (int j = 0; j < 4; ++j) cv.u4[j] = tw[row][g * 4 + j];
      *(bf16x8*)(dst + (size_t)n0 * 512 + lane * 8) = cv.h;
    }
  } else if (bid < 2338) {
    // ---- features -> A fragment image (64-row block mb)
    const int mb = bid - 2322;
    const int b0 = mb * 64;
    const int row = t >> 2, q = t & 3;
    const float4* lp = (const float4*)(lc + (size_t)(b0 + row) * 256 + q * 64);
    float s = 0.f;
#pragma unroll
    for (int j = 0; j < 16; ++j) {
      const float4 v = lp[j];
      s += fabsf(v.x) + fabsf(v.y) + fabsf(v.z) + fabsf(v.w);
    }
    s += __shfl_xor(s, 1, 64);
    s += __shfl_xor(s, 2, 64);
    if (q == 0) inv_s[row] = 1.f / (s + EPS_L1);
    __syncthreads();
#pragma unroll
    for (int i = 0; i < 9; ++i) {
      const int idx = i * 256 + t;
      const int reg = idx >> 6, l = idx & 63;
      const int c = reg >> 2, mt = reg & 3;
      const int lrow = mt * 16 + (l & 15);
      const int grow = b0 + lrow;
      const int k0 = c * 32 + (l >> 4) * 8;
      bf16x8 h;
#pragma unroll
      for (int j = 0; j < 8; ++j) {
        const int k = k0 + j;
        float v;
        if (k == 0) v = p[grow];
        else if (k <= 256) v = lc[(size_t)grow * 256 + (k - 1)] * inv_s[lrow];
        else v = other[(size_t)grow * 31 + (k - 257)];
        h[j] = (short)f2bf(v);
      }
      *(bf16x8*)(featImg + (size_t)mb * 18432 + (size_t)reg * 512 + l * 8) = h;
    }
  } else {
    // ---- zero cell_sys (1 MB)
    float4* cs4 = (float4*)cell_sys;
    const int base = (bid - 2338) * 8192 + t;
    const float4 z = {0.f, 0.f, 0.f, 0.f};
#pragma unroll
    for (int k2 = 0; k2 < 32; ++k2) cs4[base + k2 * 256] = z;
  }
}

// ---------------------------------------------------------------- k_heavyR14
// R0's k_heavyR5 verbatim (78.6 us measured): 256 blocks (8 Mb x 32 ug),
// 512 thr, 8 waves = 2 rh x 4 cq, wave tile 4mt x 4nt. A LDS-resident,
// B global->reg dist-2 (3-slot rotation), zero barriers in K-loop,
// one full __syncthreads per u-epilogue, atomic accumulate.
__global__ __launch_bounds__(512, 2) void k_heavyR14(
    const short* __restrict__ featImg, const short* __restrict__ WtB,
    const float* __restrict__ lc, const float* __restrict__ br,
    float* __restrict__ cell_sys) {
  __shared__ short aT[36864];          // 73728 B: [rh][c][mt][1KB]
  __shared__ float rsum[2][128][4];    // [par][row][cq]
  __shared__ float lcs[2][128];

  const int t = threadIdx.x, lane = t & 63, wave = t >> 6;
  const int cq = wave & 3, rh = wave >> 2;
  const int quad = lane >> 4, l15 = lane & 15;
  const int bid = blockIdx.x;
  const int Mb = bid >> 5, ug = bid & 31;   // ug%8 = XCD pin
  const int b0 = Mb * 128, u0 = ug * 8;

  // stage A (two 64-row images, linear)
  {
    const char* gA = (const char*)featImg + (size_t)Mb * 73728;
    char* lA = (char*)aT;
#pragma unroll
    for (int i = 0; i < 9; ++i)
      GLDS16(gA + i * 8192 + t * 16, lA + i * 8192 + t * 16);
  }

  const char* aB = (const char*)aT + rh * 36864 + lane * 16;   // + c*4096 + m*1024
  const char* bB = (const char*)WtB + (size_t)u0 * UIMGB + cq * 4096 + lane * 16;

  f32x4 acc[4][4], outa[4][4];
#pragma unroll
  for (int m = 0; m < 4; ++m)
#pragma unroll
    for (int n = 0; n < 4; ++n)
#pragma unroll
      for (int r = 0; r < 4; ++r) { acc[m][n][r] = 0.f; outa[m][n][r] = 0.f; }

  // B distance-2 prefetch: 3-slot static rotation
  bf16x8 bfr[3][4];
#pragma unroll
  for (int n = 0; n < 4; ++n) bfr[0][n] = *(const bf16x8*)(bB + n * 1024);
#pragma unroll
  for (int n = 0; n < 4; ++n) bfr[1][n] = *(const bf16x8*)(bB + 16384 + n * 1024);

  __syncthreads();   // A resident (drains GLDS + B prefetch harmlessly)

  // A distance-1 prefetch: 2-slot rotation; afr[0] = A[0]
  bf16x8 afr[2][4];
#pragma unroll
  for (int m = 0; m < 4; ++m) afr[0][m] = *(const bf16x8*)(aB + m * 1024);

  for (int uu = 0; uu < 8; ++uu) {
    const int u = u0 + uu;
    float bv[4];

#pragma unroll
    for (int c = 0; c < 9; ++c) {
      if (c == 0) {
#pragma unroll
        for (int n = 0; n < 4; ++n)
          bv[n] = br[(size_t)u * 256 + cq * 64 + n * 16 + l15];
        if (t < 128) lcs[uu & 1][t] = lc[(size_t)(b0 + t) * 256 + u];
      }
      // B prefetch c+2 (flat; crosses into u+1's image at c>=7)
#pragma unroll
      for (int n = 0; n < 4; ++n)
        bfr[(c + 2) % 3][n] = *(const bf16x8*)(bB + (c + 2) * 16384 + n * 1024);
      // A prefetch c+1 (skip at c==8; epilogue reloads A[0])
      if (c < 8) {
#pragma unroll
        for (int m = 0; m < 4; ++m)
          afr[(c + 1) & 1][m] = *(const bf16x8*)(aB + (c + 1) * 4096 + m * 1024);
      }
#pragma unroll
      for (int m = 0; m < 4; ++m)
#pragma unroll
        for (int n = 0; n < 4; ++n)
          acc[m][n] = MFMA16(afr[c & 1][m], bfr[c % 3][n], acc[m][n]);
    }
    bB += UIMGB;

    // issue next-u A[0] reload early (content static; hidden under epilogue)
#pragma unroll
    for (int m = 0; m < 4; ++m) afr[0][m] = *(const bf16x8*)(aB + m * 1024);

    // ---- epilogue for u: bias+relu (into acc), cross-wave rownorm, accumulate
    const int ub = uu & 1;
    float sm[4][4];
#pragma unroll
    for (int m = 0; m < 4; ++m)
#pragma unroll
      for (int r = 0; r < 4; ++r) {
        float sv = 0.f;
#pragma unroll
        for (int n = 0; n < 4; ++n) {
          const float rv = fmaxf(acc[m][n][r] + bv[n], 0.f);
          acc[m][n][r] = rv;
          sv += rv;
        }
        sm[m][r] = sv;
      }
#pragma unroll
    for (int msk = 1; msk < 16; msk <<= 1)
#pragma unroll
      for (int m = 0; m < 4; ++m)
#pragma unroll
        for (int r = 0; r < 4; ++r)
          sm[m][r] += __shfl_xor(sm[m][r], msk, 64);
    if (l15 == 0) {
#pragma unroll
      for (int m = 0; m < 4; ++m)
#pragma unroll
        for (int r = 0; r < 4; ++r)
          rsum[ub][rh * 64 + m * 16 + quad * 4 + r][cq] = sm[m][r];
    }
    __syncthreads();
#pragma unroll
    for (int m = 0; m < 4; ++m)
#pragma unroll
      for (int r = 0; r < 4; ++r) {
        const int row = rh * 64 + m * 16 + quad * 4 + r;
        const float4 rv = *(const float4*)&rsum[ub][row][0];
        const float tot = (rv.x + rv.y) + (rv.z + rv.w);
        const float alpha = lcs[ub][row] * __builtin_amdgcn_rcpf(tot);
#pragma unroll
        for (int n = 0; n < 4; ++n) {
          outa[m][n][r] = fmaf(alpha, acc[m][n][r], outa[m][n][r]);
          acc[m][n][r] = 0.f;
        }
      }
  }

#pragma unroll
  for (int m = 0; m < 4; ++m)
#pragma unroll
    for (int r = 0; r < 4; ++r) {
      const int grow = b0 + rh * 64 + m * 16 + quad * 4 + r;
#pragma unroll
      for (int n = 0; n < 4; ++n)
        atomicAdd(&cell_sys[(size_t)grow * 256 + cq * 64 + n * 16 + l15],
                  outa[m][n][r]);
    }
}

// ---------------------------------------------------------------- k_postR14
// R8's 64-block fused version: 16 rows each, cell_sys tile -> LDS,
// gates MFMA (ig,og in regs) + final combine.
__global__ __launch_bounds__(512, 2) void k_postR14(
    const short* __restrict__ featImg, const short* __restrict__ WtB,
    const float* __restrict__ bi, const float* __restrict__ bo,
    const float* __restrict__ p, const float* __restrict__ cell_sys,
    float* __restrict__ dout) {
  __shared__ short aT9[9 * 512];       // 9 KB: A fragments (c=0..8) for 16 rows
  __shared__ float cs[16 * 256];       // 16 KB: cell_sys tile
  __shared__ float rsum[16][12];
  __shared__ float ps[16];

  const int t = threadIdx.x, lane = t & 63, cg = t >> 6;
  const int quad = lane >> 4, l15 = lane & 15;
  const int mb16 = blockIdx.x, b0 = mb16 * 16;
  const int mb = mb16 >> 2, mt = mb16 & 3;

  // stage A fragments: regs (c*4 + mt), c = 0..8  -> aT9[c*1024B]
  {
    const char* gsrc = (const char*)featImg + (size_t)mb * 36864 + mt * 1024;
    char* ldst = (char*)aT9;
    GLDS16(gsrc + (size_t)(t >> 6) * 4096 + (t & 63) * 16, ldst + t * 16);
    if (t < 64)
      GLDS16(gsrc + (size_t)8 * 4096 + t * 16, ldst + 8192 + t * 16);
  }
  if (t < 16) ps[t] = p[b0 + t];

  // copy cell_sys rows [b0, b0+16) into cs
  {
    const f32x4* pp = (const f32x4*)(cell_sys + (size_t)b0 * 256);
    ((f32x4*)cs)[t] = pp[t];
    ((f32x4*)cs)[512 + t] = pp[512 + t];
  }

  f32x4 acc[2];
#pragma unroll
  for (int n = 0; n < 2; ++n)
#pragma unroll
    for (int r = 0; r < 4; ++r) acc[n][r] = 0.f;

  const char* bptr = (const char*)WtB + (size_t)256 * UIMGB + cg * 2048 + lane * 16;
  bf16x8 cb0 = *(const bf16x8*)(bptr);
  bf16x8 cb1 = *(const bf16x8*)(bptr + 1024);
  bf16x8 nb0 = *(const bf16x8*)(bptr + 16384);
  bf16x8 nb1 = *(const bf16x8*)(bptr + 16384 + 1024);
  bptr += 32768;

  __syncthreads();   // A fragments + cs resident

  float ig0[4], ig1[4], og0[4], og1[4];

#pragma unroll
  for (int g = 0; g < 2; ++g) {
    const float* bias = (g == 0) ? bi : bo;
    const float bv0 = bias[cg * 32 + l15];
    const float bv1 = bias[cg * 32 + 16 + l15];
#pragma unroll
    for (int c = 0; c < 9; ++c) {
      const bf16x8 pb0 = *(const bf16x8*)(bptr);
      const bf16x8 pb1 = *(const bf16x8*)(bptr + 1024);
      bptr += 16384;
      const bf16x8 a0 = *(const bf16x8*)((const char*)aT9 + c * 1024 + lane * 16);
      acc[0] = MFMA16(a0, cb0, acc[0]);
      acc[1] = MFMA16(a0, cb1, acc[1]);
      cb0 = nb0; cb1 = nb1; nb0 = pb0; nb1 = pb1;
    }

#pragma unroll
    for (int r = 0; r < 4; ++r) {
      const float v0 = 1.f / (1.f + __expf(-(acc[0][r] + bv0)));
      const float v1 = 1.f / (1.f + __expf(-(acc[1][r] + bv1)));
      if (g == 0) { ig0[r] = v0; ig1[r] = v1; }
      else        { og0[r] = v0; og1[r] = v1; }
      acc[0][r] = 0.f;
      acc[1][r] = 0.f;
    }

    if (g == 0) {
      float sm[4];
#pragma unroll
      for (int r = 0; r < 4; ++r) sm[r] = ig0[r] + ig1[r];
#pragma unroll
      for (int msk = 1; msk < 16; msk <<= 1)
#pragma unroll
        for (int r = 0; r < 4; ++r)
          sm[r] += __shfl_xor(sm[r], msk, 64);
      if (l15 == 0) {
#pragma unroll
        for (int r = 0; r < 4; ++r)
          rsum[quad * 4 + r][cg] = sm[r];
      }
      __syncthreads();
#pragma unroll
      for (int r = 0; r < 4; ++r) {
        const int row = quad * 4 + r;
        const float4 ra = *(const float4*)&rsum[row][0];
        const float4 rb = *(const float4*)&rsum[row][4];
        const float inv = 1.f / (((ra.x + ra.y) + (ra.z + ra.w)) +
                                 ((rb.x + rb.y) + (rb.z + rb.w)));
        ig0[r] *= inv;
        ig1[r] *= inv;
      }
    }
  }

#pragma unroll
  for (int r = 0; r < 4; ++r) {
    const int row = quad * 4 + r;
    const float pr = ps[row];
    const int ci = row * 256 + cg * 32 + l15;
    const size_t base = (size_t)(b0 + row) * 256 + cg * 32 + l15;
    {
      const float cand = fmaf(ig0[r], pr, cs[ci]);
      dout[base] = (1.f - og0[r]) * cand;
      dout[NBV + base] = og0[r] * cand;
    }
    {
      const float cand = fmaf(ig1[r], pr, cs[ci + 16]);
      dout[base + 16] = (1.f - og1[r]) * cand;
      dout[NBV + base + 16] = og1[r] * cand;
    }
  }
}

// ---------------------------------------------------------------- launch
extern "C" void kernel_launch(void* const* d_in, const int* in_sizes, int n_in,
                              void* d_out, int out_size, void* d_ws, size_t ws_size,
                              hipStream_t stream) {
  const float* lc    = (const float*)d_in[0];
  const float* p     = (const float*)d_in[1];
  const float* other = (const float*)d_in[2];
  const float* Wi    = (const float*)d_in[3];
  const float* bi    = (const float*)d_in[4];
  const float* Wr    = (const float*)d_in[5];
  const float* br    = (const float*)d_in[6];
  const float* Wo    = (const float*)d_in[7];
  const float* bo    = (const float*)d_in[8];
  float* out = (float*)d_out;

  char* wsb = (char*)d_ws;
  short* WtB      = (short*)wsb;
  short* featImg  = (short*)(wsb + WTB_BYTES);
  float* cell_sys = (float*)(wsb + WTB_BYTES + FEAT_BYTES);

  k_prep<<<2346, 256, 0, stream>>>(lc, p, other, Wi, Wr, Wo, WtB, featImg, cell_sys);
  k_heavyR14<<<256, 512, 0, stream>>>(featImg, WtB, lc, br, cell_sys);
  k_postR14<<<64, 512, 0, stream>>>(featImg, WtB, bi, bo, p, cell_sys, out);
}